// Round 3
// baseline (16425.443 us; speedup 1.0000x reference)
//
#include <hip/hip_runtime.h>
#include <hip/hip_cooperative_groups.h>
#include <math.h>

namespace cg = cooperative_groups;

#define B    32
#define H    1024
#define EMB  512
#define V    32000
#define SOS  1
#define NBLK 256
#define NTHR 1024

// PROJ tiling: 250 virtual blocks x 128 rows; k-chunk of 64 staged in LDS (dbuf)
#define PR   128
#define PKC  64
#define NVB  (V / PR)          // 250
#define NC   (H / PKC)         // 16

__global__ __launch_bounds__(NTHR, 4) void k_fused(
    const float* __restrict__ init_hidden,
    const float* __restrict__ emb,
    const float* __restrict__ wih, const float* __restrict__ bih,
    const float* __restrict__ whh, const float* __restrict__ bhh,
    const float* __restrict__ wout, const float* __restrict__ bout,
    float* __restrict__ out, float* __restrict__ ws, int T)
{
    cg::grid_group grid = cg::this_grid();
    const int t   = threadIdx.x;
    const int blk = blockIdx.x;
    const int gid = blk * NTHR + t;

    float* xT = ws;                 // [EMB][B]
    float* hA = xT + EMB * B;       // [H][B]
    float* hB = hA + H * B;         // [H][B]

    __shared__ __align__(16) char smraw[2 * PR * PKC * 4];   // 64 KiB, phase-aliased
    float* wl   = (float*)smraw;        // PROJ: [2][PR*PKC]
    float* redp = (float*)smraw;        // PROJ reduce: [4][128][8] (after k-loop, barrier-separated)
    float* redg = (float*)smraw;        // GRU reduce:  [4][128][8]
    float* sv   = (float*)smraw;        // FIN: [1024]
    float* sr   = sv + 1024;            // FIN: [1024]
    int*   si   = (int*)(sr + 1024);    // FIN: [1024]

    // ---------------- init: xT = tanh(emb[SOS]) broadcast, hA = init_hidden^T
    for (int i = gid; i < EMB * B; i += NBLK * NTHR) {
        int k = i >> 5;
        xT[i] = tanhf(emb[(size_t)SOS * EMB + k]);
    }
    for (int i = gid; i < H * B; i += NBLK * NTHR) {
        int j = i >> 5, b = i & 31;
        hA[j * B + b] = init_hidden[(size_t)b * H + j];
    }
    grid.sync();

    for (int step = 0; step < T; ++step) {
        float* hold = (step & 1) ? hB : hA;
        float* hnew = (step & 1) ? hA : hB;
        float* orow = out + (size_t)step * B * V;

        // ================= GRU: 32768 (j,b) pairs, 8-way k-split =================
        {
            const int ks = t >> 7;            // 0..7  (k-slice of 192 over 1536)
            const int pl = t & 127;           // pair-local
            const int p  = blk * 128 + pl;    // 0..32767
            const int b  = p & 31;
            const int j  = p >> 5;

            float ar = 0.f, az = 0.f, ain = 0.f, ahn = 0.f;
            const int k0 = ks * 192, k1 = k0 + 192;

            // x-part: k in [k0,k1) ∩ [0,EMB)
            const int xe = (k1 < EMB) ? k1 : EMB;
            for (int k = k0; k < xe; k += 4) {
                float u0 = xT[(k + 0) * B + b];
                float u1 = xT[(k + 1) * B + b];
                float u2 = xT[(k + 2) * B + b];
                float u3 = xT[(k + 3) * B + b];
                const float4 w0 = *(const float4*)&wih[(size_t)(0 * H + j) * EMB + k];
                const float4 w1 = *(const float4*)&wih[(size_t)(1 * H + j) * EMB + k];
                const float4 w2 = *(const float4*)&wih[(size_t)(2 * H + j) * EMB + k];
                ar  = fmaf(w0.x, u0, fmaf(w0.y, u1, fmaf(w0.z, u2, fmaf(w0.w, u3, ar))));
                az  = fmaf(w1.x, u0, fmaf(w1.y, u1, fmaf(w1.z, u2, fmaf(w1.w, u3, az))));
                ain = fmaf(w2.x, u0, fmaf(w2.y, u1, fmaf(w2.z, u2, fmaf(w2.w, u3, ain))));
            }
            // h-part: k in [k0,k1) ∩ [EMB, EMB+H)
            const int hs = (k0 > EMB) ? k0 : EMB;
            for (int k = hs; k < k1; k += 4) {
                const int kh = k - EMB;
                float u0 = hold[(kh + 0) * B + b];
                float u1 = hold[(kh + 1) * B + b];
                float u2 = hold[(kh + 2) * B + b];
                float u3 = hold[(kh + 3) * B + b];
                const float4 w0 = *(const float4*)&whh[(size_t)(0 * H + j) * H + kh];
                const float4 w1 = *(const float4*)&whh[(size_t)(1 * H + j) * H + kh];
                const float4 w2 = *(const float4*)&whh[(size_t)(2 * H + j) * H + kh];
                ar  = fmaf(w0.x, u0, fmaf(w0.y, u1, fmaf(w0.z, u2, fmaf(w0.w, u3, ar))));
                az  = fmaf(w1.x, u0, fmaf(w1.y, u1, fmaf(w1.z, u2, fmaf(w1.w, u3, az))));
                ahn = fmaf(w2.x, u0, fmaf(w2.y, u1, fmaf(w2.z, u2, fmaf(w2.w, u3, ahn))));
            }

            redg[0 * 1024 + pl * 8 + ks] = ar;
            redg[1 * 1024 + pl * 8 + ks] = az;
            redg[2 * 1024 + pl * 8 + ks] = ain;
            redg[3 * 1024 + pl * 8 + ks] = ahn;
            __syncthreads();

            if (t < 128) {
                const int pp = blk * 128 + t;
                const int bb = pp & 31, jj = pp >> 5;
                float s0 = 0.f, s1 = 0.f, s2 = 0.f, s3 = 0.f;
#pragma unroll
                for (int q = 0; q < 8; ++q) {
                    s0 += redg[0 * 1024 + t * 8 + q];
                    s1 += redg[1 * 1024 + t * 8 + q];
                    s2 += redg[2 * 1024 + t * 8 + q];
                    s3 += redg[3 * 1024 + t * 8 + q];
                }
                float gr  = s0 + bih[jj]         + bhh[jj];
                float gz  = s1 + bih[H + jj]     + bhh[H + jj];
                float gin = s2 + bih[2 * H + jj];
                float ghn = s3 + bhh[2 * H + jj];
                float r = 1.f / (1.f + expf(-gr));
                float z = 1.f / (1.f + expf(-gz));
                float n = tanhf(gin + r * ghn);   // r multiplies hh-part only
                float ho = hold[jj * B + bb];
                hnew[jj * B + bb] = (1.f - z) * n + z * ho;
            }
        }
        grid.sync();

        // ================= PROJ: logits -> orow (raw), from h_new =================
        if (blk < NVB) {
            const int rs  = t & 127;                                        // row in tile
            const int bq  = __builtin_amdgcn_readfirstlane((t >> 7) & 3);   // b-octet
            const int ks2 = __builtin_amdgcn_readfirstlane(t >> 9);         // k half
            const int r0  = blk * PR;
            const int rg  = r0 + rs;

            float acc[8];
#pragma unroll
            for (int i = 0; i < 8; ++i) acc[i] = 0.f;

            // staging helpers: 2 float4 per thread per chunk (32 KiB tile)
            const int q0 = t,        r_a = q0 >> 4, kq_a = q0 & 15;
            const int q1 = 1024 + t, r_b = q1 >> 4, kq_b = q1 & 15;
            const int off_a = r_a * PKC + ((kq_a >> 3) << 5) + 4 * ((kq_a & 7) ^ (r_a & 7));
            const int off_b = r_b * PKC + ((kq_b >> 3) << 5) + 4 * ((kq_b & 7) ^ (r_b & 7));

            float4 sA = *(const float4*)&wout[(size_t)(r0 + r_a) * H + 0 * PKC + kq_a * 4];
            float4 sB = *(const float4*)&wout[(size_t)(r0 + r_b) * H + 0 * PKC + kq_b * 4];
            *(float4*)&wl[off_a] = sA;
            *(float4*)&wl[off_b] = sB;
            __syncthreads();

            for (int c = 0; c < NC; ++c) {
                const int cur = c & 1;
                if (c + 1 < NC) {
                    sA = *(const float4*)&wout[(size_t)(r0 + r_a) * H + (c + 1) * PKC + kq_a * 4];
                    sB = *(const float4*)&wout[(size_t)(r0 + r_b) * H + (c + 1) * PKC + kq_b * 4];
                }
                const float* hcol  = hnew + (c * PKC + ks2 * 32) * B + bq * 8;   // <-- h_new (bug fix)
                const float* wbase = wl + cur * (PR * PKC) + rs * PKC + ks2 * 32;
#pragma unroll
                for (int kq = 0; kq < 8; ++kq) {
                    const float4 w = *(const float4*)&wbase[4 * (kq ^ (rs & 7))];
#pragma unroll
                    for (int j = 0; j < 4; ++j) {
                        const float wv = (j == 0) ? w.x : (j == 1) ? w.y : (j == 2) ? w.z : w.w;
                        const float* up = hcol + (kq * 4 + j) * B;
                        const float4 ua = *(const float4*)up;
                        const float4 ub = *(const float4*)(up + 4);
                        acc[0] = fmaf(wv, ua.x, acc[0]);
                        acc[1] = fmaf(wv, ua.y, acc[1]);
                        acc[2] = fmaf(wv, ua.z, acc[2]);
                        acc[3] = fmaf(wv, ua.w, acc[3]);
                        acc[4] = fmaf(wv, ub.x, acc[4]);
                        acc[5] = fmaf(wv, ub.y, acc[5]);
                        acc[6] = fmaf(wv, ub.z, acc[6]);
                        acc[7] = fmaf(wv, ub.w, acc[7]);
                    }
                }
                if (c + 1 < NC) {
                    *(float4*)&wl[(cur ^ 1) * (PR * PKC) + off_a] = sA;
                    *(float4*)&wl[(cur ^ 1) * (PR * PKC) + off_b] = sB;
                }
                __syncthreads();
            }

            // cross k-half reduction (redp aliases wl; barriers separate the uses)
            if (ks2 == 1) {
                *(float4*)&redp[(bq * 128 + rs) * 8 + 0] = make_float4(acc[0], acc[1], acc[2], acc[3]);
                *(float4*)&redp[(bq * 128 + rs) * 8 + 4] = make_float4(acc[4], acc[5], acc[6], acc[7]);
            }
            __syncthreads();
            if (ks2 == 0) {
                const float bo = bout[rg];
#pragma unroll
                for (int i = 0; i < 8; ++i) {
                    float s = acc[i] + redp[(bq * 128 + rs) * 8 + i] + bo;
                    orow[(size_t)(bq * 8 + i) * V + rg] = s;
                }
            }
        }
        grid.sync();

        // ================= FIN: log-softmax in place + argmax + next x =================
        if (blk < B) {
            const int b = blk;
            float* row = orow + (size_t)b * V;

            float m = -3.0e38f; int mi = 0;
            for (int v = t; v < V; v += NTHR) {
                float x = row[v];
                if (x > m) { m = x; mi = v; }
            }
            sv[t] = m; si[t] = mi;
            __syncthreads();
            for (int s = 512; s > 0; s >>= 1) {
                if (t < s) {
                    float ov = sv[t + s]; int oi = si[t + s];
                    if (ov > sv[t] || (ov == sv[t] && oi < si[t])) { sv[t] = ov; si[t] = oi; }
                }
                __syncthreads();
            }
            const float M = sv[0];
            const int TOK = si[0];

            float a = 0.f;
            for (int v = t; v < V; v += NTHR) a += expf(row[v] - M);
            sr[t] = a;
            __syncthreads();
            for (int s = 512; s > 0; s >>= 1) {
                if (t < s) sr[t] += sr[t + s];
                __syncthreads();
            }
            const float C = M + logf(sr[0]);

            for (int v = t; v < V; v += NTHR) row[v] -= C;

            if (t < EMB) xT[t * B + b] = tanhf(emb[(size_t)TOK * EMB + t]);
        }
        grid.sync();
    }
}

extern "C" void kernel_launch(void* const* d_in, const int* in_sizes, int n_in,
                              void* d_out, int out_size, void* d_ws, size_t ws_size,
                              hipStream_t stream)
{
    const float* p_ih   = (const float*)d_in[0];
    // d_in[1] encoder_outputs unused; d_in[2] tgt_len recovered from out_size
    const float* p_emb  = (const float*)d_in[3];
    const float* p_wih  = (const float*)d_in[4];
    const float* p_bih  = (const float*)d_in[5];
    const float* p_whh  = (const float*)d_in[6];
    const float* p_bhh  = (const float*)d_in[7];
    const float* p_wout = (const float*)d_in[8];
    const float* p_bout = (const float*)d_in[9];
    float* p_out = (float*)d_out;
    float* p_ws  = (float*)d_ws;
    int T = out_size / (B * V);

    void* args[] = { &p_ih, &p_emb, &p_wih, &p_bih, &p_whh, &p_bhh,
                     &p_wout, &p_bout, &p_out, &p_ws, &T };
    hipLaunchCooperativeKernel((void*)k_fused, dim3(NBLK), dim3(NTHR), args, 0, stream);
}